// Round 3
// baseline (1523.515 us; speedup 1.0000x reference)
//
#include <hip/hip_runtime.h>

#define B_ 4
#define S_ 2048
#define HID_ 2048
#define NH_ 16
#define NKV_ 4
#define HD_ 128
#define NTOK (B_ * S_)                 // 8192
#define QKV_N 3072                     // (NH + 2*NKV) * HD
#define KO_N 512                       // K-only row length (4 kv heads * 128)
#define SCALE_ 0.08838834764831845f    // 128^-0.5
#define NEG_ -30000.0f

typedef __attribute__((ext_vector_type(8))) short short8;
typedef __attribute__((ext_vector_type(4))) short short4v;
typedef __attribute__((ext_vector_type(4))) float f32x4;
typedef unsigned short ushort_t;
typedef unsigned int uint32;

__device__ __forceinline__ float sanit(float x) {
    if (!(x == x)) x = 0.0f;
    return fminf(fmaxf(x, -65504.0f), 65504.0f);
}
__device__ __forceinline__ ushort_t f2bf(float f) {
    union { float f; uint32 u; } c; c.f = f;
    uint32 u = c.u;
    u += 0x7fffu + ((u >> 16) & 1u);          // round-to-nearest-even
    return (ushort_t)(u >> 16);
}
__device__ __forceinline__ ushort_t f2bf_s(float f) { return f2bf(sanit(f)); }
__device__ __forceinline__ float bf2f(ushort_t h) {
    union { float f; uint32 u; } c; c.u = ((uint32)h) << 16;
    return c.f;
}

// async global->LDS, 16B per lane, linear dest (wave-uniform base + lane*16)
__device__ __forceinline__ void gl16(const ushort_t* g, ushort_t* l) {
    __builtin_amdgcn_global_load_lds(
        (__attribute__((address_space(1))) void*)g,
        (__attribute__((address_space(3))) void*)l, 16, 0, 0);
}

// ---------------------------------------------------------------------------
// Prepass 1: X fp32 [8192][2048] -> bf16 (vectorized, 8 elems/thread)
// ---------------------------------------------------------------------------
__global__ void convx_kernel(const float* __restrict__ X, ushort_t* __restrict__ Xb) {
    size_t i = (size_t)blockIdx.x * blockDim.x + threadIdx.x;
    const float4 a = *(const float4*)(X + i * 8);
    const float4 b = *(const float4*)(X + i * 8 + 4);
    short8 p;
    p[0] = (short)f2bf(a.x); p[1] = (short)f2bf(a.y);
    p[2] = (short)f2bf(a.z); p[3] = (short)f2bf(a.w);
    p[4] = (short)f2bf(b.x); p[5] = (short)f2bf(b.y);
    p[6] = (short)f2bf(b.z); p[7] = (short)f2bf(b.w);
    *(short8*)(Xb + i * 8) = p;
}

// ---------------------------------------------------------------------------
// Prepass 2: W fp32 [K][N] -> Wt bf16 [N][K] (32x32 LDS tile transpose)
// ---------------------------------------------------------------------------
__global__ void wtrans_kernel(const float* __restrict__ W, ushort_t* __restrict__ Wt,
                              int K, int N) {
    __shared__ float tile[32][33];
    const int n0 = blockIdx.x * 32;
    const int k0 = blockIdx.y * 32;
    const int t  = threadIdx.x;        // 256
    const int r  = t >> 3;             // 0..31
    const int c  = (t & 7) * 4;        // 0..28
    const float4 v = *(const float4*)(W + (size_t)(k0 + r) * N + n0 + c);
    tile[r][c] = v.x; tile[r][c + 1] = v.y; tile[r][c + 2] = v.z; tile[r][c + 3] = v.w;
    __syncthreads();
    short4v p;
    p[0] = (short)f2bf(tile[c][r]);
    p[1] = (short)f2bf(tile[c + 1][r]);
    p[2] = (short)f2bf(tile[c + 2][r]);
    p[3] = (short)f2bf(tile[c + 3][r]);
    *(short4v*)(Wt + (size_t)(n0 + r) * K + k0 + c) = p;
}

// ---------------------------------------------------------------------------
// GEMM: C = A[M,K] @ B, with B given transposed as Bt[N,K]. All bf16 in,
// fp32 acc. m97 structure: 128x128 tile, 4 waves of 64x64, BK=32,
// global_load_lds staging (no LDS writes, no staging VALU).
// SPLIT=1 (QKV): cols <2048 -> Q bf16 (C0); 2048..2559 -> K bf16 (C1);
//                2560..3071 -> V TRANSPOSED bf16 (C2)[vcol*8192 + token].
// SPLIT=0: fp32 epilogue into C0 (ld N).
// ---------------------------------------------------------------------------
template <int SPLIT>
__global__ __launch_bounds__(256, 2) void gemm_bt(
    const ushort_t* __restrict__ A, const ushort_t* __restrict__ Bt,
    void* __restrict__ C0, ushort_t* __restrict__ C1, ushort_t* __restrict__ C2,
    int M, int N, int K) {
    __shared__ __align__(16) ushort_t As[128 * 32];
    __shared__ __align__(16) ushort_t Bs[128 * 32];

    const int tid  = threadIdx.x;
    const int lane = tid & 63;
    const int w    = tid >> 6;
    const int wm   = (w >> 1) * 64;
    const int wn   = (w & 1) * 64;
    const int m0   = blockIdx.y * 128;
    const int n0   = blockIdx.x * 128;
    const int col  = lane & 15;
    const int quad = lane >> 4;

    f32x4 acc[4][4] = {};

    const int sr = tid >> 2;          // 0..63
    const int sk = (tid & 3) * 8;     // {0,8,16,24}
    const ushort_t* ag0 = A + (size_t)(m0 + sr) * K + sk;
    const ushort_t* ag1 = A + (size_t)(m0 + 64 + sr) * K + sk;
    const ushort_t* bg0 = Bt + (size_t)(n0 + sr) * K + sk;
    const ushort_t* bg1 = Bt + (size_t)(n0 + 64 + sr) * K + sk;
    ushort_t* la0 = &As[tid * 8];
    ushort_t* la1 = &As[2048 + tid * 8];
    ushort_t* lb0 = &Bs[tid * 8];
    ushort_t* lb1 = &Bs[2048 + tid * 8];

    for (int k0 = 0; k0 < K; k0 += 32) {
        __syncthreads();
        gl16(ag0 + k0, la0);
        gl16(ag1 + k0, la1);
        gl16(bg0 + k0, lb0);
        gl16(bg1 + k0, lb1);
        __syncthreads();   // compiler drains vmcnt(0) before s_barrier

        short8 af[4], bfr[4];
#pragma unroll
        for (int mt = 0; mt < 4; ++mt)
            af[mt] = *(const short8*)&As[(wm + mt * 16 + col) * 32 + quad * 8];
#pragma unroll
        for (int nt = 0; nt < 4; ++nt)
            bfr[nt] = *(const short8*)&Bs[(wn + nt * 16 + col) * 32 + quad * 8];
#pragma unroll
        for (int mt = 0; mt < 4; ++mt)
#pragma unroll
            for (int nt = 0; nt < 4; ++nt)
                acc[mt][nt] = __builtin_amdgcn_mfma_f32_16x16x32_bf16(
                    af[mt], bfr[nt], acc[mt][nt], 0, 0, 0);
    }

    if (SPLIT) {
        if (n0 >= 2560) {
            // V -> transposed global: 4 consecutive tokens packed per store
#pragma unroll
            for (int mt = 0; mt < 4; ++mt)
#pragma unroll
                for (int nt = 0; nt < 4; ++nt) {
                    int cc   = n0 + wn + nt * 16 + col - 2560;  // 0..511
                    int row0 = m0 + wm + mt * 16 + quad * 4;
                    short4v p;
#pragma unroll
                    for (int r = 0; r < 4; ++r) p[r] = (short)f2bf_s(acc[mt][nt][r]);
                    *(short4v*)&C2[(size_t)cc * NTOK + row0] = p;
                }
        } else {
            ushort_t* dst;
            int ldc, coff;
            if (n0 >= 2048) { dst = C1; ldc = KO_N; coff = 2048; }
            else            { dst = (ushort_t*)C0; ldc = HID_; coff = 0; }
#pragma unroll
            for (int mt = 0; mt < 4; ++mt)
#pragma unroll
                for (int nt = 0; nt < 4; ++nt)
#pragma unroll
                    for (int r = 0; r < 4; ++r) {
                        int row = m0 + wm + mt * 16 + quad * 4 + r;
                        int cc  = n0 + wn + nt * 16 + col - coff;
                        dst[(size_t)row * ldc + cc] = f2bf_s(acc[mt][nt][r]);
                    }
        }
    } else {
        float* dst = (float*)C0;
#pragma unroll
        for (int mt = 0; mt < 4; ++mt)
#pragma unroll
            for (int nt = 0; nt < 4; ++nt)
#pragma unroll
                for (int r = 0; r < 4; ++r) {
                    int row = m0 + wm + mt * 16 + quad * 4 + r;
                    int cc  = n0 + wn + nt * 16 + col;
                    dst[(size_t)row * N + cc] = sanit(acc[mt][nt][r]);
                }
    }
}

// ---------------------------------------------------------------------------
// RoPE in-place. Q in qbuf [8192][2048]; K in kb [8192][512].
// V (transposed) needs no RoPE. One thread per (tok, head, d<64).
// ---------------------------------------------------------------------------
__global__ void rope_kernel(ushort_t* __restrict__ qbuf,
                            ushort_t* __restrict__ kb) {
    int p = blockIdx.x * blockDim.x + threadIdx.x;
    const int total = NTOK * 20 * 64;
    if (p >= total) return;
    int d    = p & 63;
    int rest = p >> 6;
    int head = rest % 20;            // 0..15 Q, 16..19 K
    int tok  = rest / 20;
    int s    = tok & (S_ - 1);

    ushort_t* base;
    if (head < 16) base = qbuf + (size_t)tok * HID_ + head * HD_ + d;
    else           base = kb   + (size_t)tok * KO_N + (head - 16) * HD_ + d;

    float x1 = bf2f(base[0]);
    float x2 = bf2f(base[64]);

    float inv_freq = powf(10000.0f, -(float)d * (1.0f / 64.0f));
    float ang = (float)s * inv_freq;
    float sn, cs;
    sincosf(ang, &sn, &cs);

    base[0]  = f2bf_s(x1 * cs - x2 * sn);
    base[64] = f2bf_s(x2 * cs + x1 * sn);
}

// ---------------------------------------------------------------------------
// Flash attention, causal, GQA — BARRIER-FREE. 4 waves/block, each wave
// owns 16 Q rows independently (no shared LDS state, no __syncthreads).
// K/V fragments are read directly from global (kb rows / vtg d-major);
// per-(b,kvh) K+V = 1 MB -> L2/L3 resident, 16B-contiguous per lane.
// Only LDS use: wave-private Ps for the P C->A layout conversion.
// V(kt=0) fragment loads issued before softmax so latency hides under it.
// Defer-max (T13, THR=8); heavy-first block order; setprio around MFMA.
// ---------------------------------------------------------------------------
__global__ __launch_bounds__(256, 4) void flash_kernel(
    const ushort_t* __restrict__ qbuf, const ushort_t* __restrict__ kb,
    const ushort_t* __restrict__ vtg, ushort_t* __restrict__ obuf) {
    __shared__ __align__(16) ushort_t Ps[4][16][72];   // wave-private

    const int tid  = threadIdx.x;
    const int lane = tid & 63;
    const int w    = tid >> 6;                       // 0..3
    const int col  = lane & 15;
    const int quad = lane >> 4;
    const int q0   = (S_ / 64 - 1 - blockIdx.x) * 64;   // heavy blocks first
    const int h    = blockIdx.y;
    const int b    = blockIdx.z;
    const int kvh  = h >> 2;
    const int bS   = b * S_;

    const int wr    = q0 + w * 16;          // wave's first Q row
    const int i_row = wr + quad * 4;        // + r

    short8 qf[4];
    {
        const ushort_t* qp = qbuf + (size_t)(bS + wr + col) * HID_
                             + h * HD_ + quad * 8;
#pragma unroll
        for (int kt = 0; kt < 4; ++kt) qf[kt] = *(const short8*)(qp + kt * 32);
    }

    float m_i[4], l_i[4];
#pragma unroll
    for (int r = 0; r < 4; ++r) { m_i[r] = NEG_; l_i[r] = 0.f; }
    f32x4 o[8] = {};

    const int nt = wr / 64 + 1;             // per-wave exact tile count

    // global fragment bases
    const ushort_t* kbase = kb + (size_t)bS * KO_N + (size_t)kvh * HD_;
    const ushort_t* vbase = vtg + (size_t)kvh * HD_ * NTOK + bS;

    for (int t = 0; t < nt; ++t) {
        const int j0 = t * 64;

        // ---- S = Q K^T, K fragments direct from global (L2-resident) ----
        f32x4 s[4] = {};
#pragma unroll
        for (int ct = 0; ct < 4; ++ct) {
            const ushort_t* kr = kbase + (size_t)(j0 + ct * 16 + col) * KO_N + quad * 8;
            short8 kf0 = *(const short8*)(kr);
            short8 kf1 = *(const short8*)(kr + 32);
            short8 kf2 = *(const short8*)(kr + 64);
            short8 kf3 = *(const short8*)(kr + 96);
            __builtin_amdgcn_s_setprio(1);
            s[ct] = __builtin_amdgcn_mfma_f32_16x16x32_bf16(qf[0], kf0, s[ct], 0, 0, 0);
            s[ct] = __builtin_amdgcn_mfma_f32_16x16x32_bf16(qf[1], kf1, s[ct], 0, 0, 0);
            s[ct] = __builtin_amdgcn_mfma_f32_16x16x32_bf16(qf[2], kf2, s[ct], 0, 0, 0);
            s[ct] = __builtin_amdgcn_mfma_f32_16x16x32_bf16(qf[3], kf3, s[ct], 0, 0, 0);
            __builtin_amdgcn_s_setprio(0);
        }

        // ---- prefetch V fragments for kt=0; latency hides under softmax ----
        short8 vf0[8];
#pragma unroll
        for (int dt = 0; dt < 8; ++dt)
            vf0[dt] = *(const short8*)(vbase + (size_t)(dt * 16 + col) * NTOK
                                       + j0 + quad * 8);

        // ---- scale (+ causal mask only on the diagonal tile) ----
        if (j0 + 64 > wr) {
#pragma unroll
            for (int ct = 0; ct < 4; ++ct) {
                int jg = j0 + ct * 16 + col;
#pragma unroll
                for (int r = 0; r < 4; ++r)
                    s[ct][r] = (jg > i_row + r) ? NEG_ : s[ct][r] * SCALE_;
            }
        } else {
#pragma unroll
            for (int ct = 0; ct < 4; ++ct)
#pragma unroll
                for (int r = 0; r < 4; ++r) s[ct][r] *= SCALE_;
        }

        // ---- online softmax (row lives in one quad's 16 lanes) ----
        float mx[4];
#pragma unroll
        for (int r = 0; r < 4; ++r) {
            float m = fmaxf(fmaxf(s[0][r], s[1][r]), fmaxf(s[2][r], s[3][r]));
#pragma unroll
            for (int off = 1; off < 16; off <<= 1)
                m = fmaxf(m, __shfl_xor(m, off, 64));
            mx[r] = m;
        }
        // defer-max: skip rescale when max growth <= 8 (tile 0 always takes
        // the rescale path since m_i starts at NEG_, so m_i is never stale)
        int ok = 1;
#pragma unroll
        for (int r = 0; r < 4; ++r) ok &= (mx[r] <= m_i[r] + 8.0f) ? 1 : 0;
        if (!__all(ok)) {
#pragma unroll
            for (int r = 0; r < 4; ++r) {
                float mn = fmaxf(m_i[r], mx[r]);
                float a  = __expf(m_i[r] - mn);
                m_i[r] = mn;
                l_i[r] *= a;
#pragma unroll
                for (int dt = 0; dt < 8; ++dt) o[dt][r] *= a;
            }
        }
#pragma unroll
        for (int r = 0; r < 4; ++r) {
            float sum = 0.f;
#pragma unroll
            for (int ct = 0; ct < 4; ++ct) {
                float p = __expf(s[ct][r] - m_i[r]);
                s[ct][r] = p;
                sum += p;
            }
#pragma unroll
            for (int off = 1; off < 16; off <<= 1)
                sum += __shfl_xor(sum, off, 64);
            l_i[r] += sum;
        }

        // ---- P: C-layout -> LDS (wave-private, same-wave DS ordering) ----
#pragma unroll
        for (int ct = 0; ct < 4; ++ct)
#pragma unroll
            for (int r = 0; r < 4; ++r)
                Ps[w][quad * 4 + r][ct * 16 + col] = f2bf(s[ct][r]);

        // ---- O += P V : kt=0 with prefetched V, then kt=1 ----
        {
            short8 pf = *(const short8*)&Ps[w][col][quad * 8];
            __builtin_amdgcn_s_setprio(1);
#pragma unroll
            for (int dt = 0; dt < 8; ++dt)
                o[dt] = __builtin_amdgcn_mfma_f32_16x16x32_bf16(pf, vf0[dt], o[dt], 0, 0, 0);
            __builtin_amdgcn_s_setprio(0);
        }
        {
            short8 vf1[8];
#pragma unroll
            for (int dt = 0; dt < 8; ++dt)
                vf1[dt] = *(const short8*)(vbase + (size_t)(dt * 16 + col) * NTOK
                                           + j0 + 32 + quad * 8);
            short8 pf = *(const short8*)&Ps[w][col][32 + quad * 8];
            __builtin_amdgcn_s_setprio(1);
#pragma unroll
            for (int dt = 0; dt < 8; ++dt)
                o[dt] = __builtin_amdgcn_mfma_f32_16x16x32_bf16(pf, vf1[dt], o[dt], 0, 0, 0);
            __builtin_amdgcn_s_setprio(0);
        }
    }

    // epilogue: normalize + store bf16
#pragma unroll
    for (int r = 0; r < 4; ++r) {
        float inv = 1.0f / fmaxf(l_i[r], 1e-30f);
        ushort_t* op = obuf + (size_t)(bS + i_row + r) * HID_ + h * HD_;
#pragma unroll
        for (int dt = 0; dt < 8; ++dt)
            op[dt * 16 + col] = f2bf_s(o[dt][r] * inv);
    }
}

// ---------------------------------------------------------------------------
// fp32 in, fp32 out, bf16 internal.
//   d_out low  [0, 33.5MB):   Q bf16; finally fp32 result rows 0..4095
//   d_out high [33.5, 67MB):  Xb bf16 (prepass) -> O bf16 (flash) -> fp32 result
//   ws: [0, 8.4)   K bf16 rows
//       [8.4,16.8) V bf16 transposed
//       [16.8,29.4) WqkvT bf16 [3072][2048]
//       [33.5,41.9) WoT bf16 [2048][2048]
//       after flash: O copied to [0,33.5)  -> ws high-water = 41.9 MB
// ---------------------------------------------------------------------------
extern "C" void kernel_launch(void* const* d_in, const int* in_sizes, int n_in,
                              void* d_out, int out_size, void* d_ws, size_t ws_size,
                              hipStream_t stream) {
    const float* X    = (const float*)d_in[0];   // [8192, 2048] fp32
    const float* Wqkv = (const float*)d_in[1];   // [2048, 3072] fp32
    const float* Wo   = (const float*)d_in[2];   // [2048, 2048] fp32

    ushort_t* qb  = (ushort_t*)d_out;                        // Q bf16
    ushort_t* xh  = (ushort_t*)d_out + (size_t)NTOK * HID_;  // Xb, then O bf16
    ushort_t* kb  = (ushort_t*)d_ws;                         // K rows
    ushort_t* vtg = kb + (size_t)NTOK * KO_N;                // V transposed
    ushort_t* wqt = vtg + (size_t)NTOK * KO_N;               // WqkvT [3072][2048]
    ushort_t* wot = (ushort_t*)d_ws + (size_t)NTOK * HID_;   // WoT   [2048][2048]
    ushort_t* oa  = (ushort_t*)d_ws;                         // O (after copy)

    // 0) prepasses: X -> bf16 (d_out high); weights -> transposed bf16 (ws)
    convx_kernel<<<NTOK * HID_ / (256 * 8), 256, 0, stream>>>(X, xh);
    wtrans_kernel<<<dim3(QKV_N / 32, HID_ / 32), 256, 0, stream>>>(Wqkv, wqt, HID_, QKV_N);
    wtrans_kernel<<<dim3(HID_ / 32, HID_ / 32), 256, 0, stream>>>(Wo, wot, HID_, HID_);
    // 1) QKV projection: Q -> d_out low, K rows -> ws, V transposed -> ws
    gemm_bt<1><<<dim3(QKV_N / 128, NTOK / 128), 256, 0, stream>>>(
        xh, wqt, qb, kb, vtg, NTOK, QKV_N, HID_);
    // 2) RoPE on Q and K
    rope_kernel<<<(NTOK * 20 * 64) / 256, 256, 0, stream>>>(qb, kb);
    // 3) causal GQA flash attention (barrier-free): O bf16 -> d_out high
    flash_kernel<<<dim3(S_ / 64, NH_, B_), 256, 0, stream>>>(qb, kb, vtg, xh);
    // 4) move O into ws (K/V/WqkvT dead) so GEMM2 can write all of d_out
    hipMemcpyAsync(oa, xh, (size_t)NTOK * HID_ * sizeof(ushort_t),
                   hipMemcpyDeviceToDevice, stream);
    // 5) output projection: bf16 A, bf16 WoT, fp32 C -> d_out
    gemm_bt<0><<<dim3(HID_ / 128, NTOK / 128), 256, 0, stream>>>(
        oa, wot, d_out, nullptr, nullptr, NTOK, HID_, HID_);
}

// Round 4
// 744.268 us; speedup vs baseline: 2.0470x; 2.0470x over previous
//
#include <hip/hip_runtime.h>

#define B_ 4
#define S_ 2048
#define HID_ 2048
#define NH_ 16
#define NKV_ 4
#define HD_ 128
#define NTOK (B_ * S_)                 // 8192
#define QKV_N 3072                     // (NH + 2*NKV) * HD
#define KO_N 512                       // K-only row length (4 kv heads * 128)
#define SCALE_ 0.08838834764831845f    // 128^-0.5
#define NEG_ -30000.0f

typedef __attribute__((ext_vector_type(8))) short short8;
typedef __attribute__((ext_vector_type(4))) short short4v;
typedef __attribute__((ext_vector_type(4))) float f32x4;
typedef unsigned short ushort_t;
typedef unsigned int uint32;

__device__ __forceinline__ float sanit(float x) {
    if (!(x == x)) x = 0.0f;
    return fminf(fmaxf(x, -65504.0f), 65504.0f);
}
__device__ __forceinline__ ushort_t f2bf(float f) {
    union { float f; uint32 u; } c; c.f = f;
    uint32 u = c.u;
    u += 0x7fffu + ((u >> 16) & 1u);          // round-to-nearest-even
    return (ushort_t)(u >> 16);
}
__device__ __forceinline__ ushort_t f2bf_s(float f) { return f2bf(sanit(f)); }
__device__ __forceinline__ float bf2f(ushort_t h) {
    union { float f; uint32 u; } c; c.u = ((uint32)h) << 16;
    return c.f;
}

// async global->LDS, 16B per lane, linear dest (wave-uniform base + lane*16)
__device__ __forceinline__ void gl16(const ushort_t* g, ushort_t* l) {
    __builtin_amdgcn_global_load_lds(
        (__attribute__((address_space(1))) void*)g,
        (__attribute__((address_space(3))) void*)l, 16, 0, 0);
}

// ---------------------------------------------------------------------------
// Prepass 1: X fp32 [8192][2048] -> bf16 (vectorized, 8 elems/thread)
// ---------------------------------------------------------------------------
__global__ void convx_kernel(const float* __restrict__ X, ushort_t* __restrict__ Xb) {
    size_t i = (size_t)blockIdx.x * blockDim.x + threadIdx.x;
    const float4 a = *(const float4*)(X + i * 8);
    const float4 b = *(const float4*)(X + i * 8 + 4);
    short8 p;
    p[0] = (short)f2bf(a.x); p[1] = (short)f2bf(a.y);
    p[2] = (short)f2bf(a.z); p[3] = (short)f2bf(a.w);
    p[4] = (short)f2bf(b.x); p[5] = (short)f2bf(b.y);
    p[6] = (short)f2bf(b.z); p[7] = (short)f2bf(b.w);
    *(short8*)(Xb + i * 8) = p;
}

// ---------------------------------------------------------------------------
// Prepass 2: W fp32 [K][N] -> Wt bf16 [N][K] (32x32 LDS tile transpose)
// ---------------------------------------------------------------------------
__global__ void wtrans_kernel(const float* __restrict__ W, ushort_t* __restrict__ Wt,
                              int K, int N) {
    __shared__ float tile[32][33];
    const int n0 = blockIdx.x * 32;
    const int k0 = blockIdx.y * 32;
    const int t  = threadIdx.x;        // 256
    const int r  = t >> 3;             // 0..31
    const int c  = (t & 7) * 4;        // 0..28
    const float4 v = *(const float4*)(W + (size_t)(k0 + r) * N + n0 + c);
    tile[r][c] = v.x; tile[r][c + 1] = v.y; tile[r][c + 2] = v.z; tile[r][c + 3] = v.w;
    __syncthreads();
    short4v p;
    p[0] = (short)f2bf(tile[c][r]);
    p[1] = (short)f2bf(tile[c + 1][r]);
    p[2] = (short)f2bf(tile[c + 2][r]);
    p[3] = (short)f2bf(tile[c + 3][r]);
    *(short4v*)(Wt + (size_t)(n0 + r) * K + k0 + c) = p;
}

// ---------------------------------------------------------------------------
// GEMM 256x256, BK=64, 512 threads (8 waves: 2M x 4N, wave tile 128x64).
// Double-buffered LDS (128 KB), global_load_lds staging. Pipeline: all 8
// stage loads for tile t+1 issued at the top of tile t, so the boundary
// vmcnt(0) drain finds them complete (~4 MFMA clusters of hiding).
// 4 MFMA quadrant-clusters per tile with setprio + lockstep barriers.
// SPLIT=1 (QKV): cols <2048 -> Q bf16 (C0); 2048..2559 -> K bf16 (C1);
//                2560..3071 -> V TRANSPOSED bf16 (C2)[vcol*8192 + token].
// SPLIT=0: fp32 epilogue into C0 (ld N).
// ---------------------------------------------------------------------------
template <int SPLIT>
__global__ __launch_bounds__(512, 2) void gemm256(
    const ushort_t* __restrict__ A, const ushort_t* __restrict__ Bt,
    void* __restrict__ C0, ushort_t* __restrict__ C1, ushort_t* __restrict__ C2,
    int M, int N, int K) {
    __shared__ __align__(16) ushort_t As[2][256 * 64];
    __shared__ __align__(16) ushort_t Bs[2][256 * 64];

    const int tid  = threadIdx.x;          // 0..511
    const int lane = tid & 63;
    const int w    = tid >> 6;             // 0..7
    const int wm   = w >> 2;               // 0..1  row half (128 rows)
    const int wn   = w & 3;                // 0..3  col quarter (64 cols)
    const int m0   = blockIdx.y * 256;
    const int n0   = blockIdx.x * 256;
    const int col  = lane & 15;
    const int quad = lane >> 4;

    f32x4 acc[8][4] = {};

    // staging map: chunk c = i*512 + tid (i=0,1) per 128-row half;
    // row = c>>3 (0..127), kchunk = c&7 -> LDS elem = h*8192 + c*8 (lane-linear)
    const int c0_ = tid, c1_ = 512 + tid;
    const int r0_ = c0_ >> 3, kc0_ = (c0_ & 7) * 8;
    const int r1_ = c1_ >> 3, kc1_ = (c1_ & 7) * 8;

    auto stage = [&](int kt, int nb) {
        const size_t ko = (size_t)kt * 64;
#pragma unroll
        for (int h = 0; h < 2; ++h) {
            gl16(A  + (size_t)(m0 + h * 128 + r0_) * K + ko + kc0_,
                 &As[nb][h * 8192 + c0_ * 8]);
            gl16(A  + (size_t)(m0 + h * 128 + r1_) * K + ko + kc1_,
                 &As[nb][h * 8192 + c1_ * 8]);
            gl16(Bt + (size_t)(n0 + h * 128 + r0_) * K + ko + kc0_,
                 &Bs[nb][h * 8192 + c0_ * 8]);
            gl16(Bt + (size_t)(n0 + h * 128 + r1_) * K + ko + kc1_,
                 &Bs[nb][h * 8192 + c1_ * 8]);
        }
    };

    const int T = K >> 6;

    // prologue: stage tile 0, full drain
    stage(0, 0);
    asm volatile("s_waitcnt vmcnt(0)" ::: "memory");
    __builtin_amdgcn_s_barrier();

    for (int t = 0; t < T; ++t) {
        const int bi = t & 1;
        // issue next tile's 8 loads now; they land during the 4 clusters below
        stage(t + 1 < T ? t + 1 : 0, bi ^ 1);

        short8 af[4][2], bf01[2][2], bf23[2][2];

        // ---- cluster 0: A rows [wm*128 .. +63] x B cols [wn*64 .. +31] ----
#pragma unroll
        for (int mt = 0; mt < 4; ++mt)
#pragma unroll
            for (int kk = 0; kk < 2; ++kk)
                af[mt][kk] = *(const short8*)
                    &As[bi][(wm * 128 + mt * 16 + col) * 64 + kk * 32 + quad * 8];
#pragma unroll
        for (int nt = 0; nt < 2; ++nt)
#pragma unroll
            for (int kk = 0; kk < 2; ++kk)
                bf01[nt][kk] = *(const short8*)
                    &Bs[bi][(wn * 64 + nt * 16 + col) * 64 + kk * 32 + quad * 8];
        __builtin_amdgcn_s_setprio(1);
#pragma unroll
        for (int mt = 0; mt < 4; ++mt)
#pragma unroll
            for (int nt = 0; nt < 2; ++nt)
#pragma unroll
                for (int kk = 0; kk < 2; ++kk)
                    acc[mt][nt] = __builtin_amdgcn_mfma_f32_16x16x32_bf16(
                        af[mt][kk], bf01[nt][kk], acc[mt][nt], 0, 0, 0);
        __builtin_amdgcn_s_setprio(0);
        __builtin_amdgcn_s_barrier();

        // ---- cluster 1: same A rows x B cols [wn*64+32 .. +63] ----
#pragma unroll
        for (int nt = 0; nt < 2; ++nt)
#pragma unroll
            for (int kk = 0; kk < 2; ++kk)
                bf23[nt][kk] = *(const short8*)
                    &Bs[bi][(wn * 64 + (nt + 2) * 16 + col) * 64 + kk * 32 + quad * 8];
        __builtin_amdgcn_s_setprio(1);
#pragma unroll
        for (int mt = 0; mt < 4; ++mt)
#pragma unroll
            for (int nt = 0; nt < 2; ++nt)
#pragma unroll
                for (int kk = 0; kk < 2; ++kk)
                    acc[mt][nt + 2] = __builtin_amdgcn_mfma_f32_16x16x32_bf16(
                        af[mt][kk], bf23[nt][kk], acc[mt][nt + 2], 0, 0, 0);
        __builtin_amdgcn_s_setprio(0);
        __builtin_amdgcn_s_barrier();

        // ---- cluster 2: A rows [wm*128+64 .. +127] x B cols [wn*64 .. +31] ----
#pragma unroll
        for (int mt = 0; mt < 4; ++mt)
#pragma unroll
            for (int kk = 0; kk < 2; ++kk)
                af[mt][kk] = *(const short8*)
                    &As[bi][(wm * 128 + (mt + 4) * 16 + col) * 64 + kk * 32 + quad * 8];
        __builtin_amdgcn_s_setprio(1);
#pragma unroll
        for (int mt = 0; mt < 4; ++mt)
#pragma unroll
            for (int nt = 0; nt < 2; ++nt)
#pragma unroll
                for (int kk = 0; kk < 2; ++kk)
                    acc[mt + 4][nt] = __builtin_amdgcn_mfma_f32_16x16x32_bf16(
                        af[mt][kk], bf01[nt][kk], acc[mt + 4][nt], 0, 0, 0);
        __builtin_amdgcn_s_setprio(0);
        __builtin_amdgcn_s_barrier();

        // ---- cluster 3: A rows [wm*128+64 ..] x B cols [wn*64+32 ..] ----
        __builtin_amdgcn_s_setprio(1);
#pragma unroll
        for (int mt = 0; mt < 4; ++mt)
#pragma unroll
            for (int nt = 0; nt < 2; ++nt)
#pragma unroll
                for (int kk = 0; kk < 2; ++kk)
                    acc[mt + 4][nt + 2] = __builtin_amdgcn_mfma_f32_16x16x32_bf16(
                        af[mt][kk], bf23[nt][kk], acc[mt + 4][nt + 2], 0, 0, 0);
        __builtin_amdgcn_s_setprio(0);

        // ---- tile boundary: next tile fully staged by all waves ----
        asm volatile("s_waitcnt vmcnt(0)" ::: "memory");
        __builtin_amdgcn_s_barrier();
    }

    // ---- epilogue ----
    const int crow = m0 + wm * 128 + quad * 4;       // + mt*16 + r
    const int ccol = n0 + wn * 64 + col;             // + nt*16
    if (SPLIT) {
        if (n0 >= 2560) {
#pragma unroll
            for (int mt = 0; mt < 8; ++mt)
#pragma unroll
                for (int nt = 0; nt < 4; ++nt) {
                    int cc   = ccol + nt * 16 - 2560;      // 0..511
                    int row0 = crow + mt * 16;
                    short4v p;
#pragma unroll
                    for (int r = 0; r < 4; ++r) p[r] = (short)f2bf_s(acc[mt][nt][r]);
                    *(short4v*)&C2[(size_t)cc * NTOK + row0] = p;
                }
        } else {
            ushort_t* dst;
            int ldc, coff;
            if (n0 >= 2048) { dst = C1; ldc = KO_N; coff = 2048; }
            else            { dst = (ushort_t*)C0; ldc = HID_; coff = 0; }
#pragma unroll
            for (int mt = 0; mt < 8; ++mt)
#pragma unroll
                for (int nt = 0; nt < 4; ++nt)
#pragma unroll
                    for (int r = 0; r < 4; ++r) {
                        int row = crow + mt * 16 + r;
                        int cc  = ccol + nt * 16 - coff;
                        dst[(size_t)row * ldc + cc] = f2bf_s(acc[mt][nt][r]);
                    }
        }
    } else {
        float* dst = (float*)C0;
#pragma unroll
        for (int mt = 0; mt < 8; ++mt)
#pragma unroll
            for (int nt = 0; nt < 4; ++nt)
#pragma unroll
                for (int r = 0; r < 4; ++r) {
                    int row = crow + mt * 16 + r;
                    int cc  = ccol + nt * 16;
                    dst[(size_t)row * N + cc] = sanit(acc[mt][nt][r]);
                }
    }
}

// ---------------------------------------------------------------------------
// RoPE in-place. Q in qbuf [8192][2048]; K in kb [8192][512].
// V (transposed) needs no RoPE. One thread per (tok, head, d<64).
// ---------------------------------------------------------------------------
__global__ void rope_kernel(ushort_t* __restrict__ qbuf,
                            ushort_t* __restrict__ kb) {
    int p = blockIdx.x * blockDim.x + threadIdx.x;
    const int total = NTOK * 20 * 64;
    if (p >= total) return;
    int d    = p & 63;
    int rest = p >> 6;
    int head = rest % 20;            // 0..15 Q, 16..19 K
    int tok  = rest / 20;
    int s    = tok & (S_ - 1);

    ushort_t* base;
    if (head < 16) base = qbuf + (size_t)tok * HID_ + head * HD_ + d;
    else           base = kb   + (size_t)tok * KO_N + (head - 16) * HD_ + d;

    float x1 = bf2f(base[0]);
    float x2 = bf2f(base[64]);

    float inv_freq = powf(10000.0f, -(float)d * (1.0f / 64.0f));
    float ang = (float)s * inv_freq;
    float sn, cs;
    sincosf(ang, &sn, &cs);

    base[0]  = f2bf_s(x1 * cs - x2 * sn);
    base[64] = f2bf_s(x2 * cs + x1 * sn);
}

// ---------------------------------------------------------------------------
// Flash attention, causal, GQA. 8 waves, BQ=128 (16 Q rows/wave), BK=64.
// (round-1 version, measured 298 us)
// ---------------------------------------------------------------------------
__global__ __launch_bounds__(512, 4) void flash_kernel(
    const ushort_t* __restrict__ qbuf, const ushort_t* __restrict__ kb,
    const ushort_t* __restrict__ vtg, ushort_t* __restrict__ obuf) {
    __shared__ __align__(16) ushort_t Ks[64][136];   // [j][d], +8 pad
    __shared__ __align__(16) ushort_t Vt[128][72];   // [d][j], +8 pad
    __shared__ __align__(16) ushort_t Ps[8][16][72];

    const int tid  = threadIdx.x;
    const int lane = tid & 63;
    const int w    = tid >> 6;                       // 0..7
    const int col  = lane & 15;
    const int quad = lane >> 4;
    const int q0   = (S_ / 128 - 1 - blockIdx.x) * 128;  // heavy blocks first
    const int h    = blockIdx.y;
    const int b    = blockIdx.z;
    const int kvh  = h >> 2;
    const int bS   = b * S_;

    const int wr    = q0 + w * 16;          // wave's first Q row
    const int wmax  = wr + 15;              // wave's last Q row
    const int i_row = wr + quad * 4;        // + r

    short8 qf[4];
    {
        const ushort_t* qp = qbuf + (size_t)(bS + wr + col) * HID_
                             + h * HD_ + quad * 8;
#pragma unroll
        for (int kt = 0; kt < 4; ++kt) qf[kt] = *(const short8*)(qp + kt * 32);
    }

    float m_i[4], l_i[4];
#pragma unroll
    for (int r = 0; r < 4; ++r) { m_i[r] = NEG_; l_i[r] = 0.f; }
    f32x4 o[8] = {};

    const int ntiles = q0 / 64 + 2;

    // staging maps (512 threads): K 64x128, V 128x64, 2 float4/thread each
    const int jr = tid >> 3;            // 0..63
    const int kd = (tid & 7) * 16;      // 0..112
    const int vd = tid >> 2;            // 0..127
    const int vj = (tid & 3) * 16;      // 0..48

    const ushort_t* kgb = kb + (size_t)(bS + jr) * KO_N + kvh * HD_ + kd;
    const ushort_t* vgb = vtg + (size_t)(kvh * HD_ + vd) * NTOK + bS + vj;

    float4 pk0, pk1, pv0, pv1;
    // prologue: stage tile 0
    pk0 = *(const float4*)(kgb);
    pk1 = *(const float4*)(kgb + 8);
    pv0 = *(const float4*)(vgb);
    pv1 = *(const float4*)(vgb + 8);
    *(float4*)&Ks[jr][kd]     = pk0;
    *(float4*)&Ks[jr][kd + 8] = pk1;
    *(float4*)&Vt[vd][vj]     = pv0;
    *(float4*)&Vt[vd][vj + 8] = pv1;
    __syncthreads();

    for (int t = 0; t < ntiles; ++t) {
        const int j0 = t * 64;
        const bool pre = (t + 1 < ntiles);
        if (pre) {  // issue next tile's loads now; latency hides under compute
            const ushort_t* kgn = kgb + (size_t)(j0 + 64) * KO_N;
            const ushort_t* vgn = vgb + (j0 + 64);
            pk0 = *(const float4*)(kgn);
            pk1 = *(const float4*)(kgn + 8);
            pv0 = *(const float4*)(vgn);
            pv1 = *(const float4*)(vgn + 8);
        }

        if (j0 <= wmax) {   // wave-uniform: skip fully-masked tiles
            // S = Q K^T
            f32x4 s[4] = {};
#pragma unroll
            for (int ct = 0; ct < 4; ++ct)
#pragma unroll
                for (int kt = 0; kt < 4; ++kt) {
                    short8 kf = *(const short8*)&Ks[ct * 16 + col][kt * 32 + quad * 8];
                    s[ct] = __builtin_amdgcn_mfma_f32_16x16x32_bf16(qf[kt], kf, s[ct], 0, 0, 0);
                }

            // scale (+ causal mask only near the diagonal)
            if (j0 + 64 > wr) {
#pragma unroll
                for (int ct = 0; ct < 4; ++ct) {
                    int jg = j0 + ct * 16 + col;
#pragma unroll
                    for (int r = 0; r < 4; ++r)
                        s[ct][r] = (jg > i_row + r) ? NEG_ : s[ct][r] * SCALE_;
                }
            } else {
#pragma unroll
                for (int ct = 0; ct < 4; ++ct)
#pragma unroll
                    for (int r = 0; r < 4; ++r) s[ct][r] *= SCALE_;
            }

            // row max (row lives in one quad's 16 lanes)
            float mx[4];
#pragma unroll
            for (int r = 0; r < 4; ++r) {
                float m = fmaxf(fmaxf(s[0][r], s[1][r]), fmaxf(s[2][r], s[3][r]));
#pragma unroll
                for (int off = 1; off < 16; off <<= 1)
                    m = fmaxf(m, __shfl_xor(m, off, 64));
                mx[r] = m;
            }
            // defer-max: skip rescale when max growth <= 8 (rows saw a real
            // max in tile 0, so m_i is never stale-NEG on all-masked rows)
            int ok = 1;
#pragma unroll
            for (int r = 0; r < 4; ++r) ok &= (mx[r] <= m_i[r] + 8.0f) ? 1 : 0;
            if (!__all(ok)) {
#pragma unroll
                for (int r = 0; r < 4; ++r) {
                    float mn = fmaxf(m_i[r], mx[r]);
                    float a  = __expf(m_i[r] - mn);
                    m_i[r] = mn;
                    l_i[r] *= a;
#pragma unroll
                    for (int dt = 0; dt < 8; ++dt) o[dt][r] *= a;
                }
            }
#pragma unroll
            for (int r = 0; r < 4; ++r) {
                float sum = 0.f;
#pragma unroll
                for (int ct = 0; ct < 4; ++ct) {
                    float p = __expf(s[ct][r] - m_i[r]);
                    s[ct][r] = p;
                    sum += p;
                }
#pragma unroll
                for (int off = 1; off < 16; off <<= 1)
                    sum += __shfl_xor(sum, off, 64);
                l_i[r] += sum;
            }

            // P: C-layout -> LDS (wave-private; same-wave DS ordering) -> A-layout
#pragma unroll
            for (int ct = 0; ct < 4; ++ct)
#pragma unroll
                for (int r = 0; r < 4; ++r)
                    Ps[w][quad * 4 + r][ct * 16 + col] = f2bf(s[ct][r]);

            // O += P V
#pragma unroll
            for (int kt = 0; kt < 2; ++kt) {
                short8 pf = *(const short8*)&Ps[w][col][kt * 32 + quad * 8];
#pragma unroll
                for (int dt = 0; dt < 8; ++dt) {
                    short8 vf = *(const short8*)&Vt[dt * 16 + col][kt * 32 + quad * 8];
                    o[dt] = __builtin_amdgcn_mfma_f32_16x16x32_bf16(pf, vf, o[dt], 0, 0, 0);
                }
            }
        }

        __syncthreads();                 // all waves done reading Ks/Vt
        if (pre) {
            *(float4*)&Ks[jr][kd]     = pk0;
            *(float4*)&Ks[jr][kd + 8] = pk1;
            *(float4*)&Vt[vd][vj]     = pv0;
            *(float4*)&Vt[vd][vj + 8] = pv1;
            __syncthreads();             // next tile ready
        }
    }

    // epilogue: normalize + store bf16
#pragma unroll
    for (int r = 0; r < 4; ++r) {
        float inv = 1.0f / fmaxf(l_i[r], 1e-30f);
        ushort_t* op = obuf + (size_t)(bS + i_row + r) * HID_ + h * HD_;
#pragma unroll
        for (int dt = 0; dt < 8; ++dt)
            op[dt * 16 + col] = f2bf_s(o[dt][r] * inv);
    }
}

// ---------------------------------------------------------------------------
// fp32 in, fp32 out, bf16 internal.
//   d_out low  [0, 33.5MB):   Q bf16; finally fp32 result rows 0..4095
//   d_out high [33.5, 67MB):  Xb bf16 (prepass) -> O bf16 (flash) -> fp32 result
//   ws: [0, 8.4)   K bf16 rows
//       [8.4,16.8) V bf16 transposed
//       [16.8,29.4) WqkvT bf16 [3072][2048]
//       [33.5,41.9) WoT bf16 [2048][2048]
//       after flash: O copied to [0,33.5)  -> ws high-water = 41.9 MB
// ---------------------------------------------------------------------------
extern "C" void kernel_launch(void* const* d_in, const int* in_sizes, int n_in,
                              void* d_out, int out_size, void* d_ws, size_t ws_size,
                              hipStream_t stream) {
    const float* X    = (const float*)d_in[0];   // [8192, 2048] fp32
    const float* Wqkv = (const float*)d_in[1];   // [2048, 3072] fp32
    const float* Wo   = (const float*)d_in[2];   // [2048, 2048] fp32

    ushort_t* qb  = (ushort_t*)d_out;                        // Q bf16
    ushort_t* xh  = (ushort_t*)d_out + (size_t)NTOK * HID_;  // Xb, then O bf16
    ushort_t* kb  = (ushort_t*)d_ws;                         // K rows
    ushort_t* vtg = kb + (size_t)NTOK * KO_N;                // V transposed
    ushort_t* wqt = vtg + (size_t)NTOK * KO_N;               // WqkvT [3072][2048]
    ushort_t* wot = (ushort_t*)d_ws + (size_t)NTOK * HID_;   // WoT   [2048][2048]
    ushort_t* oa  = (ushort_t*)d_ws;                         // O (after copy)

    // 0) prepasses: X -> bf16 (d_out high); weights -> transposed bf16 (ws)
    convx_kernel<<<NTOK * HID_ / (256 * 8), 256, 0, stream>>>(X, xh);
    wtrans_kernel<<<dim3(QKV_N / 32, HID_ / 32), 256, 0, stream>>>(Wqkv, wqt, HID_, QKV_N);
    wtrans_kernel<<<dim3(HID_ / 32, HID_ / 32), 256, 0, stream>>>(Wo, wot, HID_, HID_);
    // 1) QKV projection: Q -> d_out low, K rows -> ws, V transposed -> ws
    gemm256<1><<<dim3(QKV_N / 256, NTOK / 256), 512, 0, stream>>>(
        xh, wqt, qb, kb, vtg, NTOK, QKV_N, HID_);
    // 2) RoPE on Q and K
    rope_kernel<<<(NTOK * 20 * 64) / 256, 256, 0, stream>>>(qb, kb);
    // 3) causal GQA flash attention: O bf16 -> d_out high (Xb dead)
    flash_kernel<<<dim3(S_ / 128, NH_, B_), 512, 0, stream>>>(qb, kb, vtg, xh);
    // 4) move O into ws (K/V/WqkvT dead) so GEMM2 can write all of d_out
    hipMemcpyAsync(oa, xh, (size_t)NTOK * HID_ * sizeof(ushort_t),
                   hipMemcpyDeviceToDevice, stream);
    // 5) output projection: bf16 A, bf16 WoT, fp32 C -> d_out
    gemm256<0><<<dim3(HID_ / 256, NTOK / 256), 512, 0, stream>>>(
        oa, wot, d_out, nullptr, nullptr, NTOK, HID_, HID_);
}

// Round 5
// 644.359 us; speedup vs baseline: 2.3644x; 1.1551x over previous
//
#include <hip/hip_runtime.h>

#define B_ 4
#define S_ 2048
#define HID_ 2048
#define NH_ 16
#define NKV_ 4
#define HD_ 128
#define NTOK (B_ * S_)                 // 8192
#define QKV_N 3072                     // (NH + 2*NKV) * HD
#define KO_N 512                       // K-only row length (4 kv heads * 128)
#define SCALE_ 0.08838834764831845f    // 128^-0.5
#define QSC_ 0.12751743f               // SCALE_ * log2(e)  (base-2 softmax)
#define NEG_ -30000.0f

typedef __attribute__((ext_vector_type(8))) short short8;
typedef __attribute__((ext_vector_type(4))) short short4v;
typedef __attribute__((ext_vector_type(4))) float f32x4;
typedef unsigned short ushort_t;
typedef unsigned int uint32;

__device__ __forceinline__ float sanit(float x) {
    if (!(x == x)) x = 0.0f;
    return fminf(fmaxf(x, -65504.0f), 65504.0f);
}
__device__ __forceinline__ ushort_t f2bf(float f) {
    union { float f; uint32 u; } c; c.f = f;
    uint32 u = c.u;
    u += 0x7fffu + ((u >> 16) & 1u);          // round-to-nearest-even
    return (ushort_t)(u >> 16);
}
__device__ __forceinline__ ushort_t f2bf_s(float f) { return f2bf(sanit(f)); }
__device__ __forceinline__ float bf2f(ushort_t h) {
    union { float f; uint32 u; } c; c.u = ((uint32)h) << 16;
    return c.f;
}

// async global->LDS, 16B per lane, linear dest (wave-uniform base + lane*16)
__device__ __forceinline__ void gl16(const ushort_t* g, ushort_t* l) {
    __builtin_amdgcn_global_load_lds(
        (__attribute__((address_space(1))) void*)g,
        (__attribute__((address_space(3))) void*)l, 16, 0, 0);
}

// ---------------------------------------------------------------------------
// Prepass 1: X fp32 [8192][2048] -> bf16 (vectorized, 8 elems/thread)
// ---------------------------------------------------------------------------
__global__ void convx_kernel(const float* __restrict__ X, ushort_t* __restrict__ Xb) {
    size_t i = (size_t)blockIdx.x * blockDim.x + threadIdx.x;
    const float4 a = *(const float4*)(X + i * 8);
    const float4 b = *(const float4*)(X + i * 8 + 4);
    short8 p;
    p[0] = (short)f2bf(a.x); p[1] = (short)f2bf(a.y);
    p[2] = (short)f2bf(a.z); p[3] = (short)f2bf(a.w);
    p[4] = (short)f2bf(b.x); p[5] = (short)f2bf(b.y);
    p[6] = (short)f2bf(b.z); p[7] = (short)f2bf(b.w);
    *(short8*)(Xb + i * 8) = p;
}

// ---------------------------------------------------------------------------
// Prepass 2: W fp32 [K][N] -> Wt bf16 [N][K] (32x32 LDS tile transpose)
// ---------------------------------------------------------------------------
__global__ void wtrans_kernel(const float* __restrict__ W, ushort_t* __restrict__ Wt,
                              int K, int N) {
    __shared__ float tile[32][33];
    const int n0 = blockIdx.x * 32;
    const int k0 = blockIdx.y * 32;
    const int t  = threadIdx.x;        // 256
    const int r  = t >> 3;             // 0..31
    const int c  = (t & 7) * 4;        // 0..28
    const float4 v = *(const float4*)(W + (size_t)(k0 + r) * N + n0 + c);
    tile[r][c] = v.x; tile[r][c + 1] = v.y; tile[r][c + 2] = v.z; tile[r][c + 3] = v.w;
    __syncthreads();
    short4v p;
    p[0] = (short)f2bf(tile[c][r]);
    p[1] = (short)f2bf(tile[c + 1][r]);
    p[2] = (short)f2bf(tile[c + 2][r]);
    p[3] = (short)f2bf(tile[c + 3][r]);
    *(short4v*)(Wt + (size_t)(n0 + r) * K + k0 + c) = p;
}

// ---------------------------------------------------------------------------
// GEMM: C = A[M,K] @ B, with B given transposed as Bt[N,K]. All bf16 in,
// fp32 acc. m97 structure: 128x128 tile, 4 waves of 64x64, BK=32,
// global_load_lds staging (no LDS writes, no staging VALU).
// SPLIT=1 (QKV): cols <2048 -> Q bf16 (C0); 2048..2559 -> K bf16 (C1);
//                2560..3071 -> V TRANSPOSED bf16 (C2)[vcol*8192 + token].
// SPLIT=0: fp32 epilogue into C0 (ld N).
// ---------------------------------------------------------------------------
template <int SPLIT>
__global__ __launch_bounds__(256, 2) void gemm_bt(
    const ushort_t* __restrict__ A, const ushort_t* __restrict__ Bt,
    void* __restrict__ C0, ushort_t* __restrict__ C1, ushort_t* __restrict__ C2,
    int M, int N, int K) {
    __shared__ __align__(16) ushort_t As[128 * 32];
    __shared__ __align__(16) ushort_t Bs[128 * 32];

    const int tid  = threadIdx.x;
    const int lane = tid & 63;
    const int w    = tid >> 6;
    const int wm   = (w >> 1) * 64;
    const int wn   = (w & 1) * 64;
    const int m0   = blockIdx.y * 128;
    const int n0   = blockIdx.x * 128;
    const int col  = lane & 15;
    const int quad = lane >> 4;

    f32x4 acc[4][4] = {};

    const int sr = tid >> 2;          // 0..63
    const int sk = (tid & 3) * 8;     // {0,8,16,24}
    const ushort_t* ag0 = A + (size_t)(m0 + sr) * K + sk;
    const ushort_t* ag1 = A + (size_t)(m0 + 64 + sr) * K + sk;
    const ushort_t* bg0 = Bt + (size_t)(n0 + sr) * K + sk;
    const ushort_t* bg1 = Bt + (size_t)(n0 + 64 + sr) * K + sk;
    ushort_t* la0 = &As[tid * 8];
    ushort_t* la1 = &As[2048 + tid * 8];
    ushort_t* lb0 = &Bs[tid * 8];
    ushort_t* lb1 = &Bs[2048 + tid * 8];

    for (int k0 = 0; k0 < K; k0 += 32) {
        __syncthreads();
        gl16(ag0 + k0, la0);
        gl16(ag1 + k0, la1);
        gl16(bg0 + k0, lb0);
        gl16(bg1 + k0, lb1);
        __syncthreads();   // compiler drains vmcnt(0) before s_barrier

        short8 af[4], bfr[4];
#pragma unroll
        for (int mt = 0; mt < 4; ++mt)
            af[mt] = *(const short8*)&As[(wm + mt * 16 + col) * 32 + quad * 8];
#pragma unroll
        for (int nt = 0; nt < 4; ++nt)
            bfr[nt] = *(const short8*)&Bs[(wn + nt * 16 + col) * 32 + quad * 8];
#pragma unroll
        for (int mt = 0; mt < 4; ++mt)
#pragma unroll
            for (int nt = 0; nt < 4; ++nt)
                acc[mt][nt] = __builtin_amdgcn_mfma_f32_16x16x32_bf16(
                    af[mt], bfr[nt], acc[mt][nt], 0, 0, 0);
    }

    if (SPLIT) {
        if (n0 >= 2560) {
            // V -> transposed global: 4 consecutive tokens packed per store
#pragma unroll
            for (int mt = 0; mt < 4; ++mt)
#pragma unroll
                for (int nt = 0; nt < 4; ++nt) {
                    int cc   = n0 + wn + nt * 16 + col - 2560;  // 0..511
                    int row0 = m0 + wm + mt * 16 + quad * 4;
                    short4v p;
#pragma unroll
                    for (int r = 0; r < 4; ++r) p[r] = (short)f2bf_s(acc[mt][nt][r]);
                    *(short4v*)&C2[(size_t)cc * NTOK + row0] = p;
                }
        } else {
            ushort_t* dst;
            int ldc, coff;
            if (n0 >= 2048) { dst = C1; ldc = KO_N; coff = 2048; }
            else            { dst = (ushort_t*)C0; ldc = HID_; coff = 0; }
#pragma unroll
            for (int mt = 0; mt < 4; ++mt)
#pragma unroll
                for (int nt = 0; nt < 4; ++nt)
#pragma unroll
                    for (int r = 0; r < 4; ++r) {
                        int row = m0 + wm + mt * 16 + quad * 4 + r;
                        int cc  = n0 + wn + nt * 16 + col - coff;
                        dst[(size_t)row * ldc + cc] = f2bf_s(acc[mt][nt][r]);
                    }
        }
    } else {
        float* dst = (float*)C0;
#pragma unroll
        for (int mt = 0; mt < 4; ++mt)
#pragma unroll
            for (int nt = 0; nt < 4; ++nt)
#pragma unroll
                for (int r = 0; r < 4; ++r) {
                    int row = m0 + wm + mt * 16 + quad * 4 + r;
                    int cc  = n0 + wn + nt * 16 + col;
                    dst[(size_t)row * N + cc] = sanit(acc[mt][nt][r]);
                }
    }
}

// ---------------------------------------------------------------------------
// RoPE in-place. Q in qbuf [8192][2048]; K in kb [8192][512].
// Q additionally pre-scaled by SCALE_*log2(e) so flash's QK^T comes out in
// the base-2 softmax domain with no per-tile scaling (K NOT scaled).
// ---------------------------------------------------------------------------
__global__ void rope_kernel(ushort_t* __restrict__ qbuf,
                            ushort_t* __restrict__ kb) {
    int p = blockIdx.x * blockDim.x + threadIdx.x;
    const int total = NTOK * 20 * 64;
    if (p >= total) return;
    int d    = p & 63;
    int rest = p >> 6;
    int head = rest % 20;            // 0..15 Q, 16..19 K
    int tok  = rest / 20;
    int s    = tok & (S_ - 1);

    ushort_t* base;
    float sc;
    if (head < 16) { base = qbuf + (size_t)tok * HID_ + head * HD_ + d; sc = QSC_; }
    else           { base = kb   + (size_t)tok * KO_N + (head - 16) * HD_ + d; sc = 1.0f; }

    float x1 = bf2f(base[0]);
    float x2 = bf2f(base[64]);

    float inv_freq = powf(10000.0f, -(float)d * (1.0f / 64.0f));
    float ang = (float)s * inv_freq;
    float sn, cs;
    sincosf(ang, &sn, &cs);

    base[0]  = f2bf_s((x1 * cs - x2 * sn) * sc);
    base[64] = f2bf_s((x2 * cs + x1 * sn) * sc);
}

// ---------------------------------------------------------------------------
// Flash attention, causal, GQA. 8 waves, BQ=128 (16 Q rows/wave), BK=64.
// Q pre-scaled (base-2 domain): interior tiles need NO elementwise fixup.
// Row-sum l computed by MFMA (P x ones) into lsum, rescaled with o under
// defer-max -> no shuffle-sum chain. Register prefetch of next K/V tile.
// ---------------------------------------------------------------------------
__global__ __launch_bounds__(512, 4) void flash_kernel(
    const ushort_t* __restrict__ qbuf, const ushort_t* __restrict__ kb,
    const ushort_t* __restrict__ vtg, ushort_t* __restrict__ obuf) {
    __shared__ __align__(16) ushort_t Ks[64][136];   // [j][d], +8 pad
    __shared__ __align__(16) ushort_t Vt[128][72];   // [d][j], +8 pad
    __shared__ __align__(16) ushort_t Ps[8][16][72];

    const int tid  = threadIdx.x;
    const int lane = tid & 63;
    const int w    = tid >> 6;                       // 0..7
    const int col  = lane & 15;
    const int quad = lane >> 4;
    const int q0   = (S_ / 128 - 1 - blockIdx.x) * 128;  // heavy blocks first
    const int h    = blockIdx.y;
    const int b    = blockIdx.z;
    const int kvh  = h >> 2;
    const int bS   = b * S_;

    const int wr    = q0 + w * 16;          // wave's first Q row
    const int wmax  = wr + 15;              // wave's last Q row
    const int i_row = wr + quad * 4;        // + r

    short8 qf[4];
    {
        const ushort_t* qp = qbuf + (size_t)(bS + wr + col) * HID_
                             + h * HD_ + quad * 8;
#pragma unroll
        for (int kt = 0; kt < 4; ++kt) qf[kt] = *(const short8*)(qp + kt * 32);
    }

    short8 vone;
#pragma unroll
    for (int e = 0; e < 8; ++e) vone[e] = (short)0x3F80;   // bf16 1.0

    float m_i[4];
#pragma unroll
    for (int r = 0; r < 4; ++r) m_i[r] = NEG_;
    f32x4 o[8] = {};
    f32x4 lsum = {};

    const int ntiles = q0 / 64 + 2;

    // staging maps (512 threads): K 64x128, V 128x64, 2 float4/thread each
    const int jr = tid >> 3;            // 0..63
    const int kd = (tid & 7) * 16;      // 0..112
    const int vd = tid >> 2;            // 0..127
    const int vj = (tid & 3) * 16;      // 0..48

    const ushort_t* kgb = kb + (size_t)(bS + jr) * KO_N + kvh * HD_ + kd;
    const ushort_t* vgb = vtg + (size_t)(kvh * HD_ + vd) * NTOK + bS + vj;

    float4 pk0, pk1, pv0, pv1;
    // prologue: stage tile 0
    pk0 = *(const float4*)(kgb);
    pk1 = *(const float4*)(kgb + 8);
    pv0 = *(const float4*)(vgb);
    pv1 = *(const float4*)(vgb + 8);
    *(float4*)&Ks[jr][kd]     = pk0;
    *(float4*)&Ks[jr][kd + 8] = pk1;
    *(float4*)&Vt[vd][vj]     = pv0;
    *(float4*)&Vt[vd][vj + 8] = pv1;
    __syncthreads();

    for (int t = 0; t < ntiles; ++t) {
        const int j0 = t * 64;
        const bool pre = (t + 1 < ntiles);
        if (pre) {  // issue next tile's loads now; latency hides under compute
            const ushort_t* kgn = kgb + (size_t)(j0 + 64) * KO_N;
            const ushort_t* vgn = vgb + (j0 + 64);
            pk0 = *(const float4*)(kgn);
            pk1 = *(const float4*)(kgn + 8);
            pv0 = *(const float4*)(vgn);
            pv1 = *(const float4*)(vgn + 8);
        }

        if (j0 <= wmax) {   // wave-uniform: skip fully-masked tiles
            // S = Q K^T  (already scaled: Q carries SCALE_*log2e)
            f32x4 s[4] = {};
#pragma unroll
            for (int ct = 0; ct < 4; ++ct)
#pragma unroll
                for (int kt = 0; kt < 4; ++kt) {
                    short8 kf = *(const short8*)&Ks[ct * 16 + col][kt * 32 + quad * 8];
                    s[ct] = __builtin_amdgcn_mfma_f32_16x16x32_bf16(qf[kt], kf, s[ct], 0, 0, 0);
                }

            // causal mask only on diagonal-adjacent tiles
            if (j0 + 64 > wr) {
#pragma unroll
                for (int ct = 0; ct < 4; ++ct) {
                    int jg = j0 + ct * 16 + col;
#pragma unroll
                    for (int r = 0; r < 4; ++r)
                        if (jg > i_row + r) s[ct][r] = NEG_;
                }
            }

            // row max (row lives in one quad's 16 lanes)
            float mx[4];
#pragma unroll
            for (int r = 0; r < 4; ++r) {
                float m = fmaxf(fmaxf(s[0][r], s[1][r]), fmaxf(s[2][r], s[3][r]));
#pragma unroll
                for (int off = 1; off < 16; off <<= 1)
                    m = fmaxf(m, __shfl_xor(m, off, 64));
                mx[r] = m;
            }
            // defer-max: skip rescale when max growth <= 8 (base-2: P <= 256)
            int ok = 1;
#pragma unroll
            for (int r = 0; r < 4; ++r) ok &= (mx[r] <= m_i[r] + 8.0f) ? 1 : 0;
            if (!__all(ok)) {
#pragma unroll
                for (int r = 0; r < 4; ++r) {
                    float mn = fmaxf(m_i[r], mx[r]);
                    float a  = exp2f(m_i[r] - mn);
                    m_i[r] = mn;
                    lsum[r] *= a;
#pragma unroll
                    for (int dt = 0; dt < 8; ++dt) o[dt][r] *= a;
                }
            }
            // P = exp2(S - m), straight to LDS; row-sum comes via MFMA below
#pragma unroll
            for (int ct = 0; ct < 4; ++ct)
#pragma unroll
                for (int r = 0; r < 4; ++r)
                    Ps[w][quad * 4 + r][ct * 16 + col] = f2bf(exp2f(s[ct][r] - m_i[r]));

            // O += P V ; lsum += P * ones  (wave-private Ps, same-wave ordering)
#pragma unroll
            for (int kt = 0; kt < 2; ++kt) {
                short8 pf = *(const short8*)&Ps[w][col][kt * 32 + quad * 8];
#pragma unroll
                for (int dt = 0; dt < 8; ++dt) {
                    short8 vf = *(const short8*)&Vt[dt * 16 + col][kt * 32 + quad * 8];
                    o[dt] = __builtin_amdgcn_mfma_f32_16x16x32_bf16(pf, vf, o[dt], 0, 0, 0);
                }
                lsum = __builtin_amdgcn_mfma_f32_16x16x32_bf16(pf, vone, lsum, 0, 0, 0);
            }
        }

        __syncthreads();                 // all waves done reading Ks/Vt
        if (pre) {
            *(float4*)&Ks[jr][kd]     = pk0;
            *(float4*)&Ks[jr][kd + 8] = pk1;
            *(float4*)&Vt[vd][vj]     = pv0;
            *(float4*)&Vt[vd][vj + 8] = pv1;
            __syncthreads();             // next tile ready
        }
    }

    // epilogue: normalize + store bf16 (lsum row mapping == o row mapping)
#pragma unroll
    for (int r = 0; r < 4; ++r) {
        float inv = 1.0f / fmaxf(lsum[r], 1e-30f);
        ushort_t* op = obuf + (size_t)(bS + i_row + r) * HID_ + h * HD_;
#pragma unroll
        for (int dt = 0; dt < 8; ++dt)
            op[dt * 16 + col] = f2bf_s(o[dt][r] * inv);
    }
}

// ---------------------------------------------------------------------------
// fp32 in, fp32 out, bf16 internal.
//   d_out low  [0, 33.5MB):   Q bf16; finally fp32 result rows 0..4095
//   d_out high [33.5, 67MB):  Xb bf16 (prepass) -> O bf16 (flash) -> fp32 result
//   ws: [0, 8.4)   K bf16 rows
//       [8.4,16.8) V bf16 transposed
//       [16.8,29.4) WqkvT bf16 [3072][2048]
//       [33.5,41.9) WoT bf16 [2048][2048]
//       after flash: O copied to [0,33.5)  -> ws high-water = 41.9 MB
// ---------------------------------------------------------------------------
extern "C" void kernel_launch(void* const* d_in, const int* in_sizes, int n_in,
                              void* d_out, int out_size, void* d_ws, size_t ws_size,
                              hipStream_t stream) {
    const float* X    = (const float*)d_in[0];   // [8192, 2048] fp32
    const float* Wqkv = (const float*)d_in[1];   // [2048, 3072] fp32
    const float* Wo   = (const float*)d_in[2];   // [2048, 2048] fp32

    ushort_t* qb  = (ushort_t*)d_out;                        // Q bf16
    ushort_t* xh  = (ushort_t*)d_out + (size_t)NTOK * HID_;  // Xb, then O bf16
    ushort_t* kb  = (ushort_t*)d_ws;                         // K rows
    ushort_t* vtg = kb + (size_t)NTOK * KO_N;                // V transposed
    ushort_t* wqt = vtg + (size_t)NTOK * KO_N;               // WqkvT [3072][2048]
    ushort_t* wot = (ushort_t*)d_ws + (size_t)NTOK * HID_;   // WoT   [2048][2048]
    ushort_t* oa  = (ushort_t*)d_ws;                         // O (after copy)

    // 0) prepasses: X -> bf16 (d_out high); weights -> transposed bf16 (ws)
    convx_kernel<<<NTOK * HID_ / (256 * 8), 256, 0, stream>>>(X, xh);
    wtrans_kernel<<<dim3(QKV_N / 32, HID_ / 32), 256, 0, stream>>>(Wqkv, wqt, HID_, QKV_N);
    wtrans_kernel<<<dim3(HID_ / 32, HID_ / 32), 256, 0, stream>>>(Wo, wot, HID_, HID_);
    // 1) QKV projection: Q -> d_out low, K rows -> ws, V transposed -> ws
    gemm_bt<1><<<dim3(QKV_N / 128, NTOK / 128), 256, 0, stream>>>(
        xh, wqt, qb, kb, vtg, NTOK, QKV_N, HID_);
    // 2) RoPE on Q and K (Q pre-scaled into base-2 softmax domain)
    rope_kernel<<<(NTOK * 20 * 64) / 256, 256, 0, stream>>>(qb, kb);
    // 3) causal GQA flash attention: O bf16 -> d_out high (Xb dead)
    flash_kernel<<<dim3(S_ / 128, NH_, B_), 512, 0, stream>>>(qb, kb, vtg, xh);
    // 4) move O into ws (K/V/WqkvT dead) so GEMM2 can write all of d_out
    hipMemcpyAsync(oa, xh, (size_t)NTOK * HID_ * sizeof(ushort_t),
                   hipMemcpyDeviceToDevice, stream);
    // 5) output projection: bf16 A, bf16 WoT, fp32 C -> d_out
    gemm_bt<0><<<dim3(HID_ / 128, NTOK / 128), 256, 0, stream>>>(
        oa, wot, d_out, nullptr, nullptr, NTOK, HID_, HID_);
}